// Round 17
// baseline (27.690 us; speedup 1.0000x reference)
//
#include <hip/hip_runtime.h>
#include <cmath>

// Problem constants (fixed by setup_inputs)
#define BB 32
#define EE 256
#define NC 1024
#define NF 4096
#define TOKSTRIDE 5120   // Nc+Nf rows per batch
#define IMG 256
#define MAXHF 64

typedef _Float16 f16x8 __attribute__((ext_vector_type(8)));
typedef float    f32x4 __attribute__((ext_vector_type(4)));

struct SampArgs {
    int i0[32]; int i1[32]; float fr[32];
    int hfl[MAXHF];   // needed hf values (sorted), nhf entries
    int inv[64];      // hf -> dense index in hfl
    int nhf, nj, jblocks;
};

// ---------------- K1: fused coarse GEMM + fine gather-GEMM (self-scanning) ----------------
// blocks [0,512): coarse role (LDS-staged, X shared by 4 waves).
// blocks [512, 512+32*jblocks): fine role -- per-wave-exclusive A rows, so the
// A fragment is loaded DIRECTLY global->registers (no LDS staging, no barrier).
__global__ __launch_bounds__(256) void k_mm(const float* __restrict__ tokens,
                                            const float* __restrict__ Wc,
                                            const float* __restrict__ bc,
                                            const float* __restrict__ Wf,
                                            const float* __restrict__ bf,
                                            const int* __restrict__ mask,
                                            float* __restrict__ coarse_img,
                                            float* __restrict__ patch_j,
                                            SampArgs sa) {
    __shared__ _Float16 Xs[64 * 256];          // 32 KB (coarse role only)
    __shared__ int csum[256];                  //  1 KB (fine role)
    __shared__ int rowsrc[64];
    const int tid  = threadIdx.x;
    const int lane = tid & 63;
    const int wave = tid >> 6;
    char* xbase = reinterpret_cast<char*>(Xs);
    const int colg = lane & 15;
    const int kg   = lane >> 4;

    if (blockIdx.x < 512) {
        // ---- coarse role: dense 64-token tile ----
        const int b  = blockIdx.x >> 4;
        const int t0 = (blockIdx.x & 15) * 64;

        const float* src = tokens + ((size_t)b * TOKSTRIDE + t0) * EE;
        #pragma unroll
        for (int i = 0; i < 8; ++i) {
            int pp  = i * 256 + tid;
            int row = pp >> 5;
            int cp  = pp & 31;
            const float* s = src + (size_t)row * EE + cp * 8;
            float4 v0 = *reinterpret_cast<const float4*>(s);
            float4 v1 = *reinterpret_cast<const float4*>(s + 4);
            f16x8 h;
            h[0] = (_Float16)v0.x; h[1] = (_Float16)v0.y;
            h[2] = (_Float16)v0.z; h[3] = (_Float16)v0.w;
            h[4] = (_Float16)v1.x; h[5] = (_Float16)v1.y;
            h[6] = (_Float16)v1.z; h[7] = (_Float16)v1.w;
            *reinterpret_cast<f16x8*>(xbase + row * 512 + ((cp ^ (row & 7)) << 4)) = h;
        }

        const int c0 = wave * 16;
        f16x8 bfrag[8];
        #pragma unroll
        for (int kt = 0; kt < 8; ++kt) {
            #pragma unroll
            for (int j = 0; j < 8; ++j) {
                int k = kt * 32 + kg * 8 + j;
                bfrag[kt][j] = (_Float16)Wc[k * 64 + c0 + colg];
            }
        }
        __syncthreads();

        f32x4 acc[4];
        #pragma unroll
        for (int mt = 0; mt < 4; ++mt) acc[mt] = (f32x4){0.f, 0.f, 0.f, 0.f};

        #pragma unroll
        for (int kt = 0; kt < 8; ++kt) {
            #pragma unroll
            for (int mt = 0; mt < 4; ++mt) {
                const int arow = mt * 16 + colg;
                const int chunk = kt * 4 + kg;
                f16x8 a = *reinterpret_cast<const f16x8*>(
                    xbase + arow * 512 + ((chunk ^ (arow & 7)) << 4));
                acc[mt] = __builtin_amdgcn_mfma_f32_16x16x32_f16(a, bfrag[kt], acc[mt], 0, 0, 0);
            }
        }

        const int col  = c0 + colg;
        const float bias = bc[col];
        const int ph = col >> 3, pw = col & 7;
        #pragma unroll
        for (int mt = 0; mt < 4; ++mt) {
            #pragma unroll
            for (int r = 0; r < 4; ++r) {
                int tg = t0 + mt * 16 + kg * 4 + r;
                int hc = tg >> 5, wc = tg & 31;
                coarse_img[(size_t)b * 65536 + (hc * 8 + ph) * 256 + wc * 8 + pw]
                    = acc[mt][r] + bias;
            }
        }
        return;
    }

    // ---- fine role: 64 needed-j's, in-block ranks, direct-reg A loads ----
    const int u0blk = blockIdx.x - 512;
    const int b  = u0blk / sa.jblocks;
    const int u0 = (u0blk - b * sa.jblocks) * 64;
    const int* m = mask + b * NF;

    // B fragments (independent of rank computation -- issue first)
    f16x8 bfrag[8];
    #pragma unroll
    for (int kt = 0; kt < 8; ++kt) {
        #pragma unroll
        for (int j = 0; j < 8; ++j) {
            int k = kt * 32 + kg * 8 + j;
            bfrag[kt][j] = (_Float16)Wf[k * 16 + colg];
        }
    }

    // chunk sums (16 mask elems per thread) + inclusive Hillis-Steele scan
    {
        int s = 0;
        const int base = tid * 16;
        #pragma unroll
        for (int i = 0; i < 16; ++i) s += (m[base + i] != 0) ? 1 : 0;
        csum[tid] = s;
    }
    __syncthreads();
    for (int off = 1; off < 256; off <<= 1) {
        int v = csum[tid];
        int add = (tid >= off) ? csum[tid - off] : 0;
        __syncthreads();
        csum[tid] = v + add;
        __syncthreads();
    }
    if (tid < 64) {
        int u = u0 + tid;
        int ridx = -1;
        if (u < sa.nj) {
            int uh = u / sa.nhf;
            int uw = u - uh * sa.nhf;
            int j  = sa.hfl[uh] * 64 + sa.hfl[uw];
            int c  = j >> 4;
            int cumj = (c > 0) ? csum[c - 1] : 0;
            bool mj = false;
            for (int i = c * 16; i <= j; ++i) {          // <=16 L3-hot loads
                bool on = (m[i] != 0);
                cumj += on ? 1 : 0;
                if (i == j) mj = on;
            }
            if (mj) ridx = cumj - 1;
        }
        rowsrc[tid] = ridx;
    }
    __syncthreads();

    // A fragment direct from global: lane covers row rowsrc[wave*16+colg],
    // k in [kt*32 + kg*8, +8) -- two contiguous float4 per kt.
    const int arow = wave * 16 + colg;
    const int ridx = rowsrc[arow];
    const int safe = (ridx >= 0) ? ridx : 0;
    const float* xsrc = tokens + ((size_t)b * TOKSTRIDE + NC + safe) * EE + kg * 8;

    f32x4 acc = {0.f, 0.f, 0.f, 0.f};
    #pragma unroll
    for (int kt = 0; kt < 8; ++kt) {
        f16x8 a = {0, 0, 0, 0, 0, 0, 0, 0};
        if (ridx >= 0) {
            float4 v0 = *reinterpret_cast<const float4*>(xsrc + kt * 32);
            float4 v1 = *reinterpret_cast<const float4*>(xsrc + kt * 32 + 4);
            a[0] = (_Float16)v0.x; a[1] = (_Float16)v0.y;
            a[2] = (_Float16)v0.z; a[3] = (_Float16)v0.w;
            a[4] = (_Float16)v1.x; a[5] = (_Float16)v1.y;
            a[6] = (_Float16)v1.z; a[7] = (_Float16)v1.w;
        }
        acc = __builtin_amdgcn_mfma_f32_16x16x32_f16(a, bfrag[kt], acc, 0, 0, 0);
    }

    const float bias = bf[colg];
    #pragma unroll
    for (int r = 0; r < 4; ++r) {
        int ol = wave * 16 + kg * 4 + r;
        int u  = u0 + ol;
        if (u < sa.nj) {
            float v = (rowsrc[ol] >= 0) ? (acc[r] + bias) : 0.f;
            patch_j[((size_t)b * sa.nj + u) * 16 + colg] = v;
        }
    }
}

// ---------------- K2: fused conv + blend + downsample (4 lanes/pixel) ----------------
__global__ __launch_bounds__(256) void k_out(const float* __restrict__ coarse_img,
                                             const float* __restrict__ patch_j,
                                             const float* __restrict__ noise,
                                             const float* __restrict__ convw,
                                             float* __restrict__ out,
                                             SampArgs sa) {
    const int gt = blockIdx.x * 256 + threadIdx.x;    // 131072 threads
    const int o  = gt >> 2;                           // output index 0..32767
    const int corner = gt & 3;
    const int a = corner >> 1, c = corner & 1;

    const int b = o >> 10;
    const int p = (o >> 5) & 31;
    const int q = o & 31;

    float kk[9];
    #pragma unroll
    for (int i = 0; i < 9; ++i) kk[i] = convw[i];

    const int   h  = a ? sa.i1[p] : sa.i0[p];
    const int   w  = c ? sa.i1[q] : sa.i0[q];
    const float fh = sa.fr[p], fw = sa.fr[q];
    const float wt = (a ? fh : 1.f - fh) * (c ? fw : 1.f - fw);

    const float* cimg = coarse_img + (size_t)b*65536;
    const float* nimg = noise      + (size_t)b*65536;

    float conv = 0.f;
    #pragma unroll
    for (int dh = -1; dh <= 1; ++dh) {
        #pragma unroll
        for (int dw = -1; dw <= 1; ++dw) {
            int hh = h + dh, wp = w + dw;
            float v = (hh >= 0 && hh < IMG && wp >= 0 && wp < IMG)
                      ? cimg[hh*IMG + wp] : 0.f;
            conv = fmaf(v, kk[(dh+1)*3 + (dw+1)], conv);
        }
    }
    const int jj = sa.inv[h >> 2] * sa.nhf + sa.inv[w >> 2];
    const int colx = (h & 3) * 4 + (w & 3);
    float fv = patch_j[((size_t)b * sa.nj + jj) * 16 + colx];

    float s = 1.f / (1.f + expf(-0.1f * nimg[h*IMG + w]));
    float val = wt * (conv * (1.f - s) + fv * s);

    val += __shfl_xor(val, 1, 64);
    val += __shfl_xor(val, 2, 64);
    if (corner == 0) out[o] = val;
}

extern "C" void kernel_launch(void* const* d_in, const int* in_sizes, int n_in,
                              void* d_out, int out_size, void* d_ws, size_t ws_size,
                              hipStream_t stream) {
    const float* tokens = (const float*)d_in[0];
    const int*   mask   = (const int*)  d_in[1];
    const float* Wc     = (const float*)d_in[2];
    const float* bc     = (const float*)d_in[3];
    const float* Wf     = (const float*)d_in[4];
    const float* bf     = (const float*)d_in[5];
    const float* convw  = (const float*)d_in[6];
    const float* noise  = (const float*)d_in[7];

    // interp + needed-hf structures (host, deterministic)
    SampArgs sa;
    bool need[64] = {false};
    for (int p = 0; p < 32; ++p) {
        double pos = (double)p * 255.0 / 31.0;
        int i0 = (int)floor(pos);
        int i1 = (i0 + 1 < 256) ? i0 + 1 : 255;
        sa.i0[p] = i0; sa.i1[p] = i1; sa.fr[p] = (float)(pos - (double)i0);
        need[i0 >> 2] = true; need[i1 >> 2] = true;
    }
    int nhf = 0;
    for (int hf = 0; hf < 64; ++hf) {
        sa.inv[hf] = 0;
        if (need[hf]) { sa.inv[hf] = nhf; sa.hfl[nhf++] = hf; }
    }
    for (int i = nhf; i < MAXHF; ++i) sa.hfl[i] = 0;
    sa.nhf = nhf;
    sa.nj  = nhf * nhf;
    sa.jblocks = (sa.nj + 63) / 64;

    float* ws = (float*)d_ws;
    float* coarse_img = ws;                               // 32*65536 floats
    float* patch_j    = ws + (size_t)BB*65536;            // 32*nj*16 floats

    k_mm <<<512 + BB * sa.jblocks, 256, 0, stream>>>(tokens, Wc, bc, Wf, bf,
                                                     mask, coarse_img, patch_j, sa);
    k_out<<<512, 256, 0, stream>>>(coarse_img, patch_j, noise, convw,
                                   (float*)d_out, sa);
}

// Round 18
// 26.592 us; speedup vs baseline: 1.0413x; 1.0413x over previous
//
#include <hip/hip_runtime.h>
#include <cmath>

// Problem constants (fixed by setup_inputs)
#define BB 32
#define EE 256
#define NC 1024
#define NF 4096
#define TOKSTRIDE 5120   // Nc+Nf rows per batch
#define IMG 256
#define MAXHF 64

typedef _Float16 f16x8 __attribute__((ext_vector_type(8)));
typedef _Float16 f16x4 __attribute__((ext_vector_type(4)));
typedef float    f32x4 __attribute__((ext_vector_type(4)));

struct SampArgs {
    int i0[32]; int i1[32]; float fr[32];
    int hfl[MAXHF];   // needed hf values (sorted), nhf entries
    int inv[64];      // hf -> dense index in hfl
    int nhf, nj, jblocks;
};

// ---------------- K1: coarse GEMM (blocks 0..511) + mask scan (blocks 512..543) ----------------
__global__ __launch_bounds__(256) void k_mm1(const float* __restrict__ tokens,
                                             const float* __restrict__ Wc,
                                             const float* __restrict__ bc,
                                             const int* __restrict__ mask,
                                             int* __restrict__ cum,
                                             float* __restrict__ coarse_img) {
    __shared__ _Float16 Xs[64 * 256];          // 32 KB (scan aliases as int*)
    const int tid  = threadIdx.x;

    if (blockIdx.x >= 512) {
        // ---- scan role ----
        int* sums = reinterpret_cast<int*>(Xs);
        const int b = blockIdx.x - 512;
        const int* m = mask + b * NF;
        int loc[16];
        int s = 0;
        #pragma unroll
        for (int i = 0; i < 16; ++i) { int v = (m[tid*16 + i] != 0) ? 1 : 0; s += v; loc[i] = s; }
        sums[tid] = s;
        __syncthreads();
        for (int off = 1; off < 256; off <<= 1) {
            int v = sums[tid];
            int add = (tid >= off) ? sums[tid - off] : 0;
            __syncthreads();
            sums[tid] = v + add;
            __syncthreads();
        }
        int excl = sums[tid] - s;
        #pragma unroll
        for (int i = 0; i < 16; ++i) cum[b*NF + tid*16 + i] = excl + loc[i];
        return;
    }

    // ---- coarse role: dense 64-token tile ----
    const int lane = tid & 63;
    const int wave = tid >> 6;
    char* xbase = reinterpret_cast<char*>(Xs);
    const int colg = lane & 15;
    const int kg   = lane >> 4;

    const int b  = blockIdx.x >> 4;
    const int t0 = (blockIdx.x & 15) * 64;

    const float* src = tokens + ((size_t)b * TOKSTRIDE + t0) * EE;
    #pragma unroll
    for (int i = 0; i < 8; ++i) {
        int pp  = i * 256 + tid;
        int row = pp >> 5;
        int cp  = pp & 31;
        const float* s = src + (size_t)row * EE + cp * 8;
        float4 v0 = *reinterpret_cast<const float4*>(s);
        float4 v1 = *reinterpret_cast<const float4*>(s + 4);
        f16x8 h;
        h[0] = (_Float16)v0.x; h[1] = (_Float16)v0.y;
        h[2] = (_Float16)v0.z; h[3] = (_Float16)v0.w;
        h[4] = (_Float16)v1.x; h[5] = (_Float16)v1.y;
        h[6] = (_Float16)v1.z; h[7] = (_Float16)v1.w;
        *reinterpret_cast<f16x8*>(xbase + row * 512 + ((cp ^ (row & 7)) << 4)) = h;
    }

    const int c0 = wave * 16;
    f16x8 bfrag[8];
    #pragma unroll
    for (int kt = 0; kt < 8; ++kt) {
        #pragma unroll
        for (int j = 0; j < 8; ++j) {
            int k = kt * 32 + kg * 8 + j;
            bfrag[kt][j] = (_Float16)Wc[k * 64 + c0 + colg];
        }
    }
    __syncthreads();

    f32x4 acc[4];
    #pragma unroll
    for (int mt = 0; mt < 4; ++mt) acc[mt] = (f32x4){0.f, 0.f, 0.f, 0.f};

    #pragma unroll
    for (int kt = 0; kt < 8; ++kt) {
        #pragma unroll
        for (int mt = 0; mt < 4; ++mt) {
            const int arow = mt * 16 + colg;
            const int chunk = kt * 4 + kg;
            f16x8 a = *reinterpret_cast<const f16x8*>(
                xbase + arow * 512 + ((chunk ^ (arow & 7)) << 4));
            acc[mt] = __builtin_amdgcn_mfma_f32_16x16x32_f16(a, bfrag[kt], acc[mt], 0, 0, 0);
        }
    }

    const int col  = c0 + colg;
    const float bias = bc[col];
    const int ph = col >> 3, pw = col & 7;
    #pragma unroll
    for (int mt = 0; mt < 4; ++mt) {
        #pragma unroll
        for (int r = 0; r < 4; ++r) {
            int tg = t0 + mt * 16 + kg * 4 + r;
            int hc = tg >> 5, wc = tg & 31;
            coarse_img[(size_t)b * 65536 + (hc * 8 + ph) * 256 + wc * 8 + pw]
                = acc[mt][r] + bias;
        }
    }
}

// ---------------- K2: sparse fine gather-GEMM over needed-j grid ----------------
__global__ __launch_bounds__(256) void k_mm2(const float* __restrict__ tokens,
                                             const float* __restrict__ Wf,
                                             const float* __restrict__ bf,
                                             const int* __restrict__ mask,
                                             const int* __restrict__ cum,
                                             float* __restrict__ patch_j,
                                             SampArgs sa) {
    __shared__ _Float16 Xs[64 * 256];          // 32 KB
    __shared__ int rowsrc[64];
    const int tid  = threadIdx.x;
    const int lane = tid & 63;
    const int wave = tid >> 6;
    char* xbase = reinterpret_cast<char*>(Xs);
    const int colg = lane & 15;
    const int kg   = lane >> 4;

    const int u0blk = blockIdx.x;
    const int b  = u0blk / sa.jblocks;
    const int u0 = (u0blk - b * sa.jblocks) * 64;

    if (tid < 64) {
        int u = u0 + tid;
        int ridx = -1;
        if (u < sa.nj) {
            int uh = u / sa.nhf;
            int uw = u - uh * sa.nhf;
            int j  = sa.hfl[uh] * 64 + sa.hfl[uw];
            if (mask[b * NF + j] != 0) ridx = cum[b * NF + j] - 1;
        }
        rowsrc[tid] = ridx;
    }
    __syncthreads();

    const int rgrp   = tid >> 6;
    const int lane64 = tid & 63;
    for (int it = 0; it < 16; ++it) {
        int rl = it * 4 + rgrp;
        int ridx = rowsrc[rl];
        int cp   = lane64 >> 1;
        int half = lane64 & 1;
        f16x4 hv = {0, 0, 0, 0};
        if (ridx >= 0) {
            const float* s = tokens + ((size_t)b * TOKSTRIDE + NC + ridx) * EE + lane64 * 4;
            float4 v = *reinterpret_cast<const float4*>(s);
            hv[0] = (_Float16)v.x; hv[1] = (_Float16)v.y;
            hv[2] = (_Float16)v.z; hv[3] = (_Float16)v.w;
        }
        *reinterpret_cast<f16x4*>(xbase + rl * 512 + (((cp ^ (rl & 7)) << 4) | (half << 3))) = hv;
    }

    f16x8 bfrag[8];
    #pragma unroll
    for (int kt = 0; kt < 8; ++kt) {
        #pragma unroll
        for (int j = 0; j < 8; ++j) {
            int k = kt * 32 + kg * 8 + j;
            bfrag[kt][j] = (_Float16)Wf[k * 16 + colg];
        }
    }
    __syncthreads();

    const int arow = wave * 16 + colg;
    const char* xrow = xbase + arow * 512;
    const int swz = arow & 7;
    f32x4 acc = {0.f, 0.f, 0.f, 0.f};
    #pragma unroll
    for (int kt = 0; kt < 8; ++kt) {
        const int chunk = kt * 4 + kg;
        f16x8 a = *reinterpret_cast<const f16x8*>(xrow + ((chunk ^ swz) << 4));
        acc = __builtin_amdgcn_mfma_f32_16x16x32_f16(a, bfrag[kt], acc, 0, 0, 0);
    }

    const float bias = bf[colg];
    #pragma unroll
    for (int r = 0; r < 4; ++r) {
        int ol = wave * 16 + kg * 4 + r;
        int u  = u0 + ol;
        if (u < sa.nj) {
            float v = (rowsrc[ol] >= 0) ? (acc[r] + bias) : 0.f;
            patch_j[((size_t)b * sa.nj + u) * 16 + colg] = v;
        }
    }
}

// ---------------- K3: fused conv + blend + downsample (4 lanes/pixel) ----------------
__global__ __launch_bounds__(256) void k_out(const float* __restrict__ coarse_img,
                                             const float* __restrict__ patch_j,
                                             const float* __restrict__ noise,
                                             const float* __restrict__ convw,
                                             float* __restrict__ out,
                                             SampArgs sa) {
    const int gt = blockIdx.x * 256 + threadIdx.x;    // 131072 threads
    const int o  = gt >> 2;                           // output index 0..32767
    const int corner = gt & 3;
    const int a = corner >> 1, c = corner & 1;

    const int b = o >> 10;
    const int p = (o >> 5) & 31;
    const int q = o & 31;

    float kk[9];
    #pragma unroll
    for (int i = 0; i < 9; ++i) kk[i] = convw[i];

    const int   h  = a ? sa.i1[p] : sa.i0[p];
    const int   w  = c ? sa.i1[q] : sa.i0[q];
    const float fh = sa.fr[p], fw = sa.fr[q];
    const float wt = (a ? fh : 1.f - fh) * (c ? fw : 1.f - fw);

    const float* cimg = coarse_img + (size_t)b*65536;
    const float* nimg = noise      + (size_t)b*65536;

    float conv = 0.f;
    #pragma unroll
    for (int dh = -1; dh <= 1; ++dh) {
        #pragma unroll
        for (int dw = -1; dw <= 1; ++dw) {
            int hh = h + dh, wp = w + dw;
            float v = (hh >= 0 && hh < IMG && wp >= 0 && wp < IMG)
                      ? cimg[hh*IMG + wp] : 0.f;
            conv = fmaf(v, kk[(dh+1)*3 + (dw+1)], conv);
        }
    }
    const int jj = sa.inv[h >> 2] * sa.nhf + sa.inv[w >> 2];
    const int colx = (h & 3) * 4 + (w & 3);
    float fv = patch_j[((size_t)b * sa.nj + jj) * 16 + colx];

    float s = 1.f / (1.f + expf(-0.1f * nimg[h*IMG + w]));
    float val = wt * (conv * (1.f - s) + fv * s);

    val += __shfl_xor(val, 1, 64);
    val += __shfl_xor(val, 2, 64);
    if (corner == 0) out[o] = val;
}

extern "C" void kernel_launch(void* const* d_in, const int* in_sizes, int n_in,
                              void* d_out, int out_size, void* d_ws, size_t ws_size,
                              hipStream_t stream) {
    const float* tokens = (const float*)d_in[0];
    const int*   mask   = (const int*)  d_in[1];
    const float* Wc     = (const float*)d_in[2];
    const float* bc     = (const float*)d_in[3];
    const float* Wf     = (const float*)d_in[4];
    const float* bf     = (const float*)d_in[5];
    const float* convw  = (const float*)d_in[6];
    const float* noise  = (const float*)d_in[7];

    // interp + needed-hf structures (host, deterministic)
    SampArgs sa;
    bool need[64] = {false};
    for (int p = 0; p < 32; ++p) {
        double pos = (double)p * 255.0 / 31.0;
        int i0 = (int)floor(pos);
        int i1 = (i0 + 1 < 256) ? i0 + 1 : 255;
        sa.i0[p] = i0; sa.i1[p] = i1; sa.fr[p] = (float)(pos - (double)i0);
        need[i0 >> 2] = true; need[i1 >> 2] = true;
    }
    int nhf = 0;
    for (int hf = 0; hf < 64; ++hf) {
        sa.inv[hf] = 0;
        if (need[hf]) { sa.inv[hf] = nhf; sa.hfl[nhf++] = hf; }
    }
    for (int i = nhf; i < MAXHF; ++i) sa.hfl[i] = 0;
    sa.nhf = nhf;
    sa.nj  = nhf * nhf;
    sa.jblocks = (sa.nj + 63) / 64;

    float* ws = (float*)d_ws;
    float* coarse_img = ws;                               // 32*65536 floats
    float* patch_j    = ws + (size_t)BB*65536;            // 32*nj*16 floats
    int*   cum        = (int*)(ws + (size_t)2*BB*65536);  // 32*4096 ints

    k_mm1<<<544, 256, 0, stream>>>(tokens, Wc, bc, mask, cum, coarse_img);
    k_mm2<<<BB * sa.jblocks, 256, 0, stream>>>(tokens, Wf, bf, mask, cum,
                                               patch_j, sa);
    k_out<<<512, 256, 0, stream>>>(coarse_img, patch_j, noise, convw,
                                   (float*)d_out, sa);
}

// Round 19
// 23.766 us; speedup vs baseline: 1.1652x; 1.1189x over previous
//
#include <hip/hip_runtime.h>
#include <cmath>

// Problem constants (fixed by setup_inputs)
#define BB 32
#define EE 256
#define NC 1024
#define NF 4096
#define TOKSTRIDE 5120   // Nc+Nf rows per batch
#define IMG 256
#define MAXHF 64

typedef _Float16 f16x8 __attribute__((ext_vector_type(8)));
typedef _Float16 f16x4 __attribute__((ext_vector_type(4)));
typedef float    f32x4 __attribute__((ext_vector_type(4)));

struct SampArgs {
    int i0[32]; int i1[32]; float fr[32];
    int hfl[MAXHF];   // needed hf values (sorted), nhf entries
    int inv[64];      // hf -> dense index in hfl
    int nhf, nj, jblocks;
};

// ---------------- K1: fused fine gather-GEMM (first) + coarse GEMM (last) ----------------
// blocks [0, 32*jblocks): fine role -- longest serial chain (in-block scan +
// gather), scheduled FIRST so it overlaps maximally; blocks [32*jblocks, +512):
// coarse role -- shorter MFMA-dense chain, forms the dispatch tail.
__global__ __launch_bounds__(256) void k_mm(const float* __restrict__ tokens,
                                            const float* __restrict__ Wc,
                                            const float* __restrict__ bc,
                                            const float* __restrict__ Wf,
                                            const float* __restrict__ bf,
                                            const int* __restrict__ mask,
                                            float* __restrict__ coarse_img,
                                            float* __restrict__ patch_j,
                                            SampArgs sa) {
    __shared__ _Float16 Xs[64 * 256];          // 32 KB
    __shared__ int csum[256];                  //  1 KB (fine role)
    __shared__ int rowsrc[64];
    const int tid  = threadIdx.x;
    const int lane = tid & 63;
    const int wave = tid >> 6;
    char* xbase = reinterpret_cast<char*>(Xs);
    const int colg = lane & 15;
    const int kg   = lane >> 4;
    const int NFINE = BB * sa.jblocks;

    if ((int)blockIdx.x >= NFINE) {
        // ---- coarse role: dense 64-token tile ----
        const int t  = blockIdx.x - NFINE;
        const int b  = t >> 4;
        const int t0 = (t & 15) * 64;

        const float* src = tokens + ((size_t)b * TOKSTRIDE + t0) * EE;
        #pragma unroll
        for (int i = 0; i < 8; ++i) {
            int pp  = i * 256 + tid;
            int row = pp >> 5;
            int cp  = pp & 31;
            const float* s = src + (size_t)row * EE + cp * 8;
            float4 v0 = *reinterpret_cast<const float4*>(s);
            float4 v1 = *reinterpret_cast<const float4*>(s + 4);
            f16x8 h;
            h[0] = (_Float16)v0.x; h[1] = (_Float16)v0.y;
            h[2] = (_Float16)v0.z; h[3] = (_Float16)v0.w;
            h[4] = (_Float16)v1.x; h[5] = (_Float16)v1.y;
            h[6] = (_Float16)v1.z; h[7] = (_Float16)v1.w;
            *reinterpret_cast<f16x8*>(xbase + row * 512 + ((cp ^ (row & 7)) << 4)) = h;
        }

        const int c0 = wave * 16;
        f16x8 bfrag[8];
        #pragma unroll
        for (int kt = 0; kt < 8; ++kt) {
            #pragma unroll
            for (int j = 0; j < 8; ++j) {
                int k = kt * 32 + kg * 8 + j;
                bfrag[kt][j] = (_Float16)Wc[k * 64 + c0 + colg];
            }
        }
        __syncthreads();

        f32x4 acc[4];
        #pragma unroll
        for (int mt = 0; mt < 4; ++mt) acc[mt] = (f32x4){0.f, 0.f, 0.f, 0.f};

        #pragma unroll
        for (int kt = 0; kt < 8; ++kt) {
            #pragma unroll
            for (int mt = 0; mt < 4; ++mt) {
                const int arow = mt * 16 + colg;
                const int chunk = kt * 4 + kg;
                f16x8 a = *reinterpret_cast<const f16x8*>(
                    xbase + arow * 512 + ((chunk ^ (arow & 7)) << 4));
                acc[mt] = __builtin_amdgcn_mfma_f32_16x16x32_f16(a, bfrag[kt], acc[mt], 0, 0, 0);
            }
        }

        const int col  = c0 + colg;
        const float bias = bc[col];
        const int ph = col >> 3, pw = col & 7;
        #pragma unroll
        for (int mt = 0; mt < 4; ++mt) {
            #pragma unroll
            for (int r = 0; r < 4; ++r) {
                int tg = t0 + mt * 16 + kg * 4 + r;
                int hc = tg >> 5, wc = tg & 31;
                coarse_img[(size_t)b * 65536 + (hc * 8 + ph) * 256 + wc * 8 + pw]
                    = acc[mt][r] + bias;
            }
        }
        return;
    }

    // ---- fine role: 64 needed-j's, in-block rank computation ----
    const int u0blk = blockIdx.x;
    const int b  = u0blk / sa.jblocks;
    const int u0 = (u0blk - b * sa.jblocks) * 64;
    const int* m = mask + b * NF;

    // chunk sums (16 mask elems per thread) + inclusive Hillis-Steele scan
    {
        int s = 0;
        const int base = tid * 16;
        #pragma unroll
        for (int i = 0; i < 16; ++i) s += (m[base + i] != 0) ? 1 : 0;
        csum[tid] = s;
    }
    __syncthreads();
    for (int off = 1; off < 256; off <<= 1) {
        int v = csum[tid];
        int add = (tid >= off) ? csum[tid - off] : 0;
        __syncthreads();
        csum[tid] = v + add;
        __syncthreads();
    }
    if (tid < 64) {
        int u = u0 + tid;
        int ridx = -1;
        if (u < sa.nj) {
            int uh = u / sa.nhf;
            int uw = u - uh * sa.nhf;
            int j  = sa.hfl[uh] * 64 + sa.hfl[uw];
            int c  = j >> 4;
            int cumj = (c > 0) ? csum[c - 1] : 0;
            bool mj = false;
            for (int i = c * 16; i <= j; ++i) {          // <=16 L3-hot loads
                bool on = (m[i] != 0);
                cumj += on ? 1 : 0;
                if (i == j) mj = on;
            }
            if (mj) ridx = cumj - 1;
        }
        rowsrc[tid] = ridx;
    }
    __syncthreads();

    // stage gathered rows (4 rows/iter, 64 lanes x float4 per row)
    const int rgrp   = tid >> 6;
    const int lane64 = tid & 63;
    for (int it = 0; it < 16; ++it) {
        int rl = it * 4 + rgrp;
        int ridx = rowsrc[rl];
        int cp   = lane64 >> 1;
        int half = lane64 & 1;
        f16x4 hv = {0, 0, 0, 0};
        if (ridx >= 0) {
            const float* s = tokens + ((size_t)b * TOKSTRIDE + NC + ridx) * EE + lane64 * 4;
            float4 v = *reinterpret_cast<const float4*>(s);
            hv[0] = (_Float16)v.x; hv[1] = (_Float16)v.y;
            hv[2] = (_Float16)v.z; hv[3] = (_Float16)v.w;
        }
        *reinterpret_cast<f16x4*>(xbase + rl * 512 + (((cp ^ (rl & 7)) << 4) | (half << 3))) = hv;
    }

    f16x8 bfrag[8];
    #pragma unroll
    for (int kt = 0; kt < 8; ++kt) {
        #pragma unroll
        for (int j = 0; j < 8; ++j) {
            int k = kt * 32 + kg * 8 + j;
            bfrag[kt][j] = (_Float16)Wf[k * 16 + colg];
        }
    }
    __syncthreads();

    const int arow = wave * 16 + colg;
    const char* xrow = xbase + arow * 512;
    const int swz = arow & 7;
    f32x4 acc = {0.f, 0.f, 0.f, 0.f};
    #pragma unroll
    for (int kt = 0; kt < 8; ++kt) {
        const int chunk = kt * 4 + kg;
        f16x8 a = *reinterpret_cast<const f16x8*>(xrow + ((chunk ^ swz) << 4));
        acc = __builtin_amdgcn_mfma_f32_16x16x32_f16(a, bfrag[kt], acc, 0, 0, 0);
    }

    const float bias = bf[colg];
    #pragma unroll
    for (int r = 0; r < 4; ++r) {
        int ol = wave * 16 + kg * 4 + r;
        int u  = u0 + ol;
        if (u < sa.nj) {
            float v = (rowsrc[ol] >= 0) ? (acc[r] + bias) : 0.f;
            patch_j[((size_t)b * sa.nj + u) * 16 + colg] = v;
        }
    }
}

// ---------------- K2: fused conv + blend + downsample (4 lanes/pixel) ----------------
__global__ __launch_bounds__(256) void k_out(const float* __restrict__ coarse_img,
                                             const float* __restrict__ patch_j,
                                             const float* __restrict__ noise,
                                             const float* __restrict__ convw,
                                             float* __restrict__ out,
                                             SampArgs sa) {
    const int gt = blockIdx.x * 256 + threadIdx.x;    // 131072 threads
    const int o  = gt >> 2;                           // output index 0..32767
    const int corner = gt & 3;
    const int a = corner >> 1, c = corner & 1;

    const int b = o >> 10;
    const int p = (o >> 5) & 31;
    const int q = o & 31;

    float kk[9];
    #pragma unroll
    for (int i = 0; i < 9; ++i) kk[i] = convw[i];

    const int   h  = a ? sa.i1[p] : sa.i0[p];
    const int   w  = c ? sa.i1[q] : sa.i0[q];
    const float fh = sa.fr[p], fw = sa.fr[q];
    const float wt = (a ? fh : 1.f - fh) * (c ? fw : 1.f - fw);

    const float* cimg = coarse_img + (size_t)b*65536;
    const float* nimg = noise      + (size_t)b*65536;

    float conv = 0.f;
    #pragma unroll
    for (int dh = -1; dh <= 1; ++dh) {
        #pragma unroll
        for (int dw = -1; dw <= 1; ++dw) {
            int hh = h + dh, wp = w + dw;
            float v = (hh >= 0 && hh < IMG && wp >= 0 && wp < IMG)
                      ? cimg[hh*IMG + wp] : 0.f;
            conv = fmaf(v, kk[(dh+1)*3 + (dw+1)], conv);
        }
    }
    const int jj = sa.inv[h >> 2] * sa.nhf + sa.inv[w >> 2];
    const int colx = (h & 3) * 4 + (w & 3);
    float fv = patch_j[((size_t)b * sa.nj + jj) * 16 + colx];

    float s = 1.f / (1.f + expf(-0.1f * nimg[h*IMG + w]));
    float val = wt * (conv * (1.f - s) + fv * s);

    val += __shfl_xor(val, 1, 64);
    val += __shfl_xor(val, 2, 64);
    if (corner == 0) out[o] = val;
}

extern "C" void kernel_launch(void* const* d_in, const int* in_sizes, int n_in,
                              void* d_out, int out_size, void* d_ws, size_t ws_size,
                              hipStream_t stream) {
    const float* tokens = (const float*)d_in[0];
    const int*   mask   = (const int*)  d_in[1];
    const float* Wc     = (const float*)d_in[2];
    const float* bc     = (const float*)d_in[3];
    const float* Wf     = (const float*)d_in[4];
    const float* bf     = (const float*)d_in[5];
    const float* convw  = (const float*)d_in[6];
    const float* noise  = (const float*)d_in[7];

    // interp + needed-hf structures (host, deterministic)
    SampArgs sa;
    bool need[64] = {false};
    for (int p = 0; p < 32; ++p) {
        double pos = (double)p * 255.0 / 31.0;
        int i0 = (int)floor(pos);
        int i1 = (i0 + 1 < 256) ? i0 + 1 : 255;
        sa.i0[p] = i0; sa.i1[p] = i1; sa.fr[p] = (float)(pos - (double)i0);
        need[i0 >> 2] = true; need[i1 >> 2] = true;
    }
    int nhf = 0;
    for (int hf = 0; hf < 64; ++hf) {
        sa.inv[hf] = 0;
        if (need[hf]) { sa.inv[hf] = nhf; sa.hfl[nhf++] = hf; }
    }
    for (int i = nhf; i < MAXHF; ++i) sa.hfl[i] = 0;
    sa.nhf = nhf;
    sa.nj  = nhf * nhf;
    sa.jblocks = (sa.nj + 63) / 64;

    float* ws = (float*)d_ws;
    float* coarse_img = ws;                               // 32*65536 floats
    float* patch_j    = ws + (size_t)BB*65536;            // 32*nj*16 floats

    k_mm <<<BB * sa.jblocks + 512, 256, 0, stream>>>(tokens, Wc, bc, Wf, bf,
                                                     mask, coarse_img, patch_j, sa);
    k_out<<<512, 256, 0, stream>>>(coarse_img, patch_j, noise, convw,
                                   (float*)d_out, sa);
}

// Round 20
// 22.752 us; speedup vs baseline: 1.2171x; 1.0446x over previous
//
#include <hip/hip_runtime.h>
#include <cmath>

// Problem constants (fixed by setup_inputs)
#define BB 32
#define EE 256
#define NC 1024
#define NF 4096
#define TOKSTRIDE 5120   // Nc+Nf rows per batch
#define IMG 256
#define MAXHF 64

typedef _Float16 f16x8 __attribute__((ext_vector_type(8)));
typedef _Float16 f16x4 __attribute__((ext_vector_type(4)));
typedef float    f32x4 __attribute__((ext_vector_type(4)));

struct SampArgs {
    int i0[32]; int i1[32]; float fr[32];
    int hfl[MAXHF];   // needed hf values (sorted), nhf entries
    int inv[64];      // hf -> dense index in hfl
    int nhf, nj, jblocks;
};

// ---------------- K1: fused fine gather-GEMM (first) + coarse GEMM (last) ----------------
// Fine role first: longest serial chain overlaps maximally; coarse tail is
// MFMA-dense and short. Fine scan via wave shfl (2 barriers, was 16).
__global__ __launch_bounds__(256) void k_mm(const float* __restrict__ tokens,
                                            const float* __restrict__ Wc,
                                            const float* __restrict__ bc,
                                            const float* __restrict__ Wf,
                                            const float* __restrict__ bf,
                                            const int* __restrict__ mask,
                                            float* __restrict__ coarse_img,
                                            float* __restrict__ patch_j,
                                            SampArgs sa) {
    __shared__ _Float16 Xs[64 * 256];          // 32 KB
    __shared__ int csum[256];                  //  1 KB (fine role)
    __shared__ int wsum[4];
    __shared__ int rowsrc[64];
    const int tid  = threadIdx.x;
    const int lane = tid & 63;
    const int wave = tid >> 6;
    char* xbase = reinterpret_cast<char*>(Xs);
    const int colg = lane & 15;
    const int kg   = lane >> 4;
    const int NFINE = BB * sa.jblocks;

    if ((int)blockIdx.x >= NFINE) {
        // ---- coarse role: dense 64-token tile ----
        const int t  = blockIdx.x - NFINE;
        const int b  = t >> 4;
        const int t0 = (t & 15) * 64;

        const float* src = tokens + ((size_t)b * TOKSTRIDE + t0) * EE;
        #pragma unroll
        for (int i = 0; i < 8; ++i) {
            int pp  = i * 256 + tid;
            int row = pp >> 5;
            int cp  = pp & 31;
            const float* s = src + (size_t)row * EE + cp * 8;
            float4 v0 = *reinterpret_cast<const float4*>(s);
            float4 v1 = *reinterpret_cast<const float4*>(s + 4);
            f16x8 h;
            h[0] = (_Float16)v0.x; h[1] = (_Float16)v0.y;
            h[2] = (_Float16)v0.z; h[3] = (_Float16)v0.w;
            h[4] = (_Float16)v1.x; h[5] = (_Float16)v1.y;
            h[6] = (_Float16)v1.z; h[7] = (_Float16)v1.w;
            *reinterpret_cast<f16x8*>(xbase + row * 512 + ((cp ^ (row & 7)) << 4)) = h;
        }

        const int c0 = wave * 16;
        f16x8 bfrag[8];
        #pragma unroll
        for (int kt = 0; kt < 8; ++kt) {
            #pragma unroll
            for (int j = 0; j < 8; ++j) {
                int k = kt * 32 + kg * 8 + j;
                bfrag[kt][j] = (_Float16)Wc[k * 64 + c0 + colg];
            }
        }
        __syncthreads();

        f32x4 acc[4];
        #pragma unroll
        for (int mt = 0; mt < 4; ++mt) acc[mt] = (f32x4){0.f, 0.f, 0.f, 0.f};

        #pragma unroll
        for (int kt = 0; kt < 8; ++kt) {
            #pragma unroll
            for (int mt = 0; mt < 4; ++mt) {
                const int arow = mt * 16 + colg;
                const int chunk = kt * 4 + kg;
                f16x8 a = *reinterpret_cast<const f16x8*>(
                    xbase + arow * 512 + ((chunk ^ (arow & 7)) << 4));
                acc[mt] = __builtin_amdgcn_mfma_f32_16x16x32_f16(a, bfrag[kt], acc[mt], 0, 0, 0);
            }
        }

        const int col  = c0 + colg;
        const float bias = bc[col];
        const int ph = col >> 3, pw = col & 7;
        #pragma unroll
        for (int mt = 0; mt < 4; ++mt) {
            #pragma unroll
            for (int r = 0; r < 4; ++r) {
                int tg = t0 + mt * 16 + kg * 4 + r;
                int hc = tg >> 5, wc = tg & 31;
                coarse_img[(size_t)b * 65536 + (hc * 8 + ph) * 256 + wc * 8 + pw]
                    = acc[mt][r] + bias;
            }
        }
        return;
    }

    // ---- fine role: 64 needed-j's, in-block rank computation ----
    const int u0blk = blockIdx.x;
    const int b  = u0blk / sa.jblocks;
    const int u0 = (u0blk - b * sa.jblocks) * 64;
    const int* m = mask + b * NF;

    // chunk sums (16 mask elems per thread, int4 loads) + wave-shfl scan
    {
        const int base = tid * 16;
        int4 m0 = *reinterpret_cast<const int4*>(m + base);
        int4 m1 = *reinterpret_cast<const int4*>(m + base + 4);
        int4 m2 = *reinterpret_cast<const int4*>(m + base + 8);
        int4 m3 = *reinterpret_cast<const int4*>(m + base + 12);
        int s = (m0.x!=0)+(m0.y!=0)+(m0.z!=0)+(m0.w!=0)
              + (m1.x!=0)+(m1.y!=0)+(m1.z!=0)+(m1.w!=0)
              + (m2.x!=0)+(m2.y!=0)+(m2.z!=0)+(m2.w!=0)
              + (m3.x!=0)+(m3.y!=0)+(m3.z!=0)+(m3.w!=0);
        int v = s;
        #pragma unroll
        for (int off = 1; off < 64; off <<= 1) {
            int t = __shfl_up(v, off, 64);
            if (lane >= off) v += t;
        }
        if (lane == 63) wsum[wave] = v;
        __syncthreads();
        int add = 0;
        #pragma unroll
        for (int w2 = 0; w2 < 4; ++w2) add += (w2 < wave) ? wsum[w2] : 0;
        csum[tid] = v + add;
    }
    __syncthreads();

    if (tid < 64) {
        int u = u0 + tid;
        int ridx = -1;
        if (u < sa.nj) {
            int uh = u / sa.nhf;
            int uw = u - uh * sa.nhf;
            int j  = sa.hfl[uh] * 64 + sa.hfl[uw];
            int c  = j >> 4;
            int base = c * 16;
            int off  = j - base;            // 0..15
            int4 m0 = *reinterpret_cast<const int4*>(m + base);
            int4 m1 = *reinterpret_cast<const int4*>(m + base + 4);
            int4 m2 = *reinterpret_cast<const int4*>(m + base + 8);
            int4 m3 = *reinterpret_cast<const int4*>(m + base + 12);
            int cumj = (c > 0) ? csum[c - 1] : 0;
            bool mj = false;
            #pragma unroll
            for (int i = 0; i < 16; ++i) {
                int mv = (i < 4) ? (&m0.x)[i] : (i < 8) ? (&m1.x)[i-4]
                       : (i < 12) ? (&m2.x)[i-8] : (&m3.x)[i-12];
                bool on = (mv != 0);
                cumj += (i <= off && on) ? 1 : 0;
                if (i == off) mj = on;
            }
            if (mj) ridx = cumj - 1;
        }
        rowsrc[tid] = ridx;
    }
    __syncthreads();

    // stage gathered rows (4 rows/iter, 64 lanes x float4 per row)
    const int rgrp   = tid >> 6;
    const int lane64 = tid & 63;
    for (int it = 0; it < 16; ++it) {
        int rl = it * 4 + rgrp;
        int ridx = rowsrc[rl];
        int cp   = lane64 >> 1;
        int half = lane64 & 1;
        f16x4 hv = {0, 0, 0, 0};
        if (ridx >= 0) {
            const float* s = tokens + ((size_t)b * TOKSTRIDE + NC + ridx) * EE + lane64 * 4;
            float4 v = *reinterpret_cast<const float4*>(s);
            hv[0] = (_Float16)v.x; hv[1] = (_Float16)v.y;
            hv[2] = (_Float16)v.z; hv[3] = (_Float16)v.w;
        }
        *reinterpret_cast<f16x4*>(xbase + rl * 512 + (((cp ^ (rl & 7)) << 4) | (half << 3))) = hv;
    }

    f16x8 bfrag[8];
    #pragma unroll
    for (int kt = 0; kt < 8; ++kt) {
        #pragma unroll
        for (int j = 0; j < 8; ++j) {
            int k = kt * 32 + kg * 8 + j;
            bfrag[kt][j] = (_Float16)Wf[k * 16 + colg];
        }
    }
    __syncthreads();

    const int arow = wave * 16 + colg;
    const char* xrow = xbase + arow * 512;
    const int swz = arow & 7;
    f32x4 acc = {0.f, 0.f, 0.f, 0.f};
    #pragma unroll
    for (int kt = 0; kt < 8; ++kt) {
        const int chunk = kt * 4 + kg;
        f16x8 a = *reinterpret_cast<const f16x8*>(xrow + ((chunk ^ swz) << 4));
        acc = __builtin_amdgcn_mfma_f32_16x16x32_f16(a, bfrag[kt], acc, 0, 0, 0);
    }

    const float bias = bf[colg];
    #pragma unroll
    for (int r = 0; r < 4; ++r) {
        int ol = wave * 16 + kg * 4 + r;
        int u  = u0 + ol;
        if (u < sa.nj) {
            float v = (rowsrc[ol] >= 0) ? (acc[r] + bias) : 0.f;
            patch_j[((size_t)b * sa.nj + u) * 16 + colg] = v;
        }
    }
}

// ---------------- K2: fused conv + blend + downsample (4 lanes/pixel) ----------------
__global__ __launch_bounds__(256) void k_out(const float* __restrict__ coarse_img,
                                             const float* __restrict__ patch_j,
                                             const float* __restrict__ noise,
                                             const float* __restrict__ convw,
                                             float* __restrict__ out,
                                             SampArgs sa) {
    const int gt = blockIdx.x * 256 + threadIdx.x;    // 131072 threads
    const int o  = gt >> 2;                           // output index 0..32767
    const int corner = gt & 3;
    const int a = corner >> 1, c = corner & 1;

    const int b = o >> 10;
    const int p = (o >> 5) & 31;
    const int q = o & 31;

    float kk[9];
    #pragma unroll
    for (int i = 0; i < 9; ++i) kk[i] = convw[i];

    const int   h  = a ? sa.i1[p] : sa.i0[p];
    const int   w  = c ? sa.i1[q] : sa.i0[q];
    const float fh = sa.fr[p], fw = sa.fr[q];
    const float wt = (a ? fh : 1.f - fh) * (c ? fw : 1.f - fw);

    const float* cimg = coarse_img + (size_t)b*65536;
    const float* nimg = noise      + (size_t)b*65536;

    float conv = 0.f;
    #pragma unroll
    for (int dh = -1; dh <= 1; ++dh) {
        #pragma unroll
        for (int dw = -1; dw <= 1; ++dw) {
            int hh = h + dh, wp = w + dw;
            float v = (hh >= 0 && hh < IMG && wp >= 0 && wp < IMG)
                      ? cimg[hh*IMG + wp] : 0.f;
            conv = fmaf(v, kk[(dh+1)*3 + (dw+1)], conv);
        }
    }
    const int jj = sa.inv[h >> 2] * sa.nhf + sa.inv[w >> 2];
    const int colx = (h & 3) * 4 + (w & 3);
    float fv = patch_j[((size_t)b * sa.nj + jj) * 16 + colx];

    float s = 1.f / (1.f + expf(-0.1f * nimg[h*IMG + w]));
    float val = wt * (conv * (1.f - s) + fv * s);

    val += __shfl_xor(val, 1, 64);
    val += __shfl_xor(val, 2, 64);
    if (corner == 0) out[o] = val;
}

extern "C" void kernel_launch(void* const* d_in, const int* in_sizes, int n_in,
                              void* d_out, int out_size, void* d_ws, size_t ws_size,
                              hipStream_t stream) {
    const float* tokens = (const float*)d_in[0];
    const int*   mask   = (const int*)  d_in[1];
    const float* Wc     = (const float*)d_in[2];
    const float* bc     = (const float*)d_in[3];
    const float* Wf     = (const float*)d_in[4];
    const float* bf     = (const float*)d_in[5];
    const float* convw  = (const float*)d_in[6];
    const float* noise  = (const float*)d_in[7];

    // interp + needed-hf structures (host, deterministic)
    SampArgs sa;
    bool need[64] = {false};
    for (int p = 0; p < 32; ++p) {
        double pos = (double)p * 255.0 / 31.0;
        int i0 = (int)floor(pos);
        int i1 = (i0 + 1 < 256) ? i0 + 1 : 255;
        sa.i0[p] = i0; sa.i1[p] = i1; sa.fr[p] = (float)(pos - (double)i0);
        need[i0 >> 2] = true; need[i1 >> 2] = true;
    }
    int nhf = 0;
    for (int hf = 0; hf < 64; ++hf) {
        sa.inv[hf] = 0;
        if (need[hf]) { sa.inv[hf] = nhf; sa.hfl[nhf++] = hf; }
    }
    for (int i = nhf; i < MAXHF; ++i) sa.hfl[i] = 0;
    sa.nhf = nhf;
    sa.nj  = nhf * nhf;
    sa.jblocks = (sa.nj + 63) / 64;

    float* ws = (float*)d_ws;
    float* coarse_img = ws;                               // 32*65536 floats
    float* patch_j    = ws + (size_t)BB*65536;            // 32*nj*16 floats

    k_mm <<<BB * sa.jblocks + 512, 256, 0, stream>>>(tokens, Wc, bc, Wf, bf,
                                                     mask, coarse_img, patch_j, sa);
    k_out<<<512, 256, 0, stream>>>(coarse_img, patch_j, noise, convw,
                                   (float*)d_out, sa);
}

// Round 21
// 22.339 us; speedup vs baseline: 1.2396x; 1.0185x over previous
//
#include <hip/hip_runtime.h>
#include <cmath>

// Problem constants (fixed by setup_inputs)
#define BB 32
#define EE 256
#define NC 1024
#define NF 4096
#define TOKSTRIDE 5120   // Nc+Nf rows per batch
#define IMG 256
#define MAXHF 64

typedef _Float16 f16x8 __attribute__((ext_vector_type(8)));
typedef _Float16 f16x4 __attribute__((ext_vector_type(4)));
typedef float    f32x4 __attribute__((ext_vector_type(4)));

struct SampArgs {
    int i0[32]; int i1[32]; float fr[32];
    int hfl[MAXHF];   // needed hf values (sorted), nhf entries
    int inv[64];      // hf -> dense index in hfl
    int nhf, nj, jblocks;
};

// ---------------- K1: fused fine gather-GEMM (first) + coarse GEMM (last) ----------------
// Fine role first: longest serial chain overlaps maximally; coarse tail is
// MFMA-dense and short. Fine scan via wave shfl (2 barriers).
__global__ __launch_bounds__(256) void k_mm(const float* __restrict__ tokens,
                                            const float* __restrict__ Wc,
                                            const float* __restrict__ bc,
                                            const float* __restrict__ Wf,
                                            const float* __restrict__ bf,
                                            const int* __restrict__ mask,
                                            float* __restrict__ coarse_img,
                                            float* __restrict__ patch_j,
                                            SampArgs sa) {
    __shared__ _Float16 Xs[64 * 256];          // 32 KB
    __shared__ int csum[256];                  //  1 KB (fine role)
    __shared__ int wsum[4];
    __shared__ int rowsrc[64];
    const int tid  = threadIdx.x;
    const int lane = tid & 63;
    const int wave = tid >> 6;
    char* xbase = reinterpret_cast<char*>(Xs);
    const int colg = lane & 15;
    const int kg   = lane >> 4;
    const int NFINE = BB * sa.jblocks;

    if ((int)blockIdx.x >= NFINE) {
        // ---- coarse role: dense 64-token tile ----
        const int t  = blockIdx.x - NFINE;
        const int b  = t >> 4;
        const int t0 = (t & 15) * 64;

        const float* src = tokens + ((size_t)b * TOKSTRIDE + t0) * EE;
        #pragma unroll
        for (int i = 0; i < 8; ++i) {
            int pp  = i * 256 + tid;
            int row = pp >> 5;
            int cp  = pp & 31;
            const float* s = src + (size_t)row * EE + cp * 8;
            float4 v0 = *reinterpret_cast<const float4*>(s);
            float4 v1 = *reinterpret_cast<const float4*>(s + 4);
            f16x8 h;
            h[0] = (_Float16)v0.x; h[1] = (_Float16)v0.y;
            h[2] = (_Float16)v0.z; h[3] = (_Float16)v0.w;
            h[4] = (_Float16)v1.x; h[5] = (_Float16)v1.y;
            h[6] = (_Float16)v1.z; h[7] = (_Float16)v1.w;
            *reinterpret_cast<f16x8*>(xbase + row * 512 + ((cp ^ (row & 7)) << 4)) = h;
        }

        const int c0 = wave * 16;
        f16x8 bfrag[8];
        #pragma unroll
        for (int kt = 0; kt < 8; ++kt) {
            #pragma unroll
            for (int j = 0; j < 8; ++j) {
                int k = kt * 32 + kg * 8 + j;
                bfrag[kt][j] = (_Float16)Wc[k * 64 + c0 + colg];
            }
        }
        __syncthreads();

        f32x4 acc[4];
        #pragma unroll
        for (int mt = 0; mt < 4; ++mt) acc[mt] = (f32x4){0.f, 0.f, 0.f, 0.f};

        #pragma unroll
        for (int kt = 0; kt < 8; ++kt) {
            #pragma unroll
            for (int mt = 0; mt < 4; ++mt) {
                const int arow = mt * 16 + colg;
                const int chunk = kt * 4 + kg;
                f16x8 a = *reinterpret_cast<const f16x8*>(
                    xbase + arow * 512 + ((chunk ^ (arow & 7)) << 4));
                acc[mt] = __builtin_amdgcn_mfma_f32_16x16x32_f16(a, bfrag[kt], acc[mt], 0, 0, 0);
            }
        }

        const int col  = c0 + colg;
        const float bias = bc[col];
        const int ph = col >> 3, pw = col & 7;
        #pragma unroll
        for (int mt = 0; mt < 4; ++mt) {
            #pragma unroll
            for (int r = 0; r < 4; ++r) {
                int tg = t0 + mt * 16 + kg * 4 + r;
                int hc = tg >> 5, wc = tg & 31;
                coarse_img[(size_t)b * 65536 + (hc * 8 + ph) * 256 + wc * 8 + pw]
                    = acc[mt][r] + bias;
            }
        }
        return;
    }

    // ---- fine role: 64 needed-j's, in-block rank computation ----
    const int u0blk = blockIdx.x;
    const int b  = u0blk / sa.jblocks;
    const int u0 = (u0blk - b * sa.jblocks) * 64;
    const int* m = mask + b * NF;

    // chunk sums (16 mask elems per thread, int4 loads) + wave-shfl scan
    {
        const int base = tid * 16;
        int4 m0 = *reinterpret_cast<const int4*>(m + base);
        int4 m1 = *reinterpret_cast<const int4*>(m + base + 4);
        int4 m2 = *reinterpret_cast<const int4*>(m + base + 8);
        int4 m3 = *reinterpret_cast<const int4*>(m + base + 12);
        int s = (m0.x!=0)+(m0.y!=0)+(m0.z!=0)+(m0.w!=0)
              + (m1.x!=0)+(m1.y!=0)+(m1.z!=0)+(m1.w!=0)
              + (m2.x!=0)+(m2.y!=0)+(m2.z!=0)+(m2.w!=0)
              + (m3.x!=0)+(m3.y!=0)+(m3.z!=0)+(m3.w!=0);
        int v = s;
        #pragma unroll
        for (int off = 1; off < 64; off <<= 1) {
            int t = __shfl_up(v, off, 64);
            if (lane >= off) v += t;
        }
        if (lane == 63) wsum[wave] = v;
        __syncthreads();
        int add = 0;
        #pragma unroll
        for (int w2 = 0; w2 < 4; ++w2) add += (w2 < wave) ? wsum[w2] : 0;
        csum[tid] = v + add;
    }
    __syncthreads();

    if (tid < 64) {
        int u = u0 + tid;
        int ridx = -1;
        if (u < sa.nj) {
            int uh = u / sa.nhf;
            int uw = u - uh * sa.nhf;
            int j  = sa.hfl[uh] * 64 + sa.hfl[uw];
            int c  = j >> 4;
            int base = c * 16;
            int off  = j - base;            // 0..15
            int4 m0 = *reinterpret_cast<const int4*>(m + base);
            int4 m1 = *reinterpret_cast<const int4*>(m + base + 4);
            int4 m2 = *reinterpret_cast<const int4*>(m + base + 8);
            int4 m3 = *reinterpret_cast<const int4*>(m + base + 12);
            int cumj = (c > 0) ? csum[c - 1] : 0;
            bool mj = false;
            #pragma unroll
            for (int i = 0; i < 16; ++i) {
                int mv = (i < 4) ? (&m0.x)[i] : (i < 8) ? (&m1.x)[i-4]
                       : (i < 12) ? (&m2.x)[i-8] : (&m3.x)[i-12];
                bool on = (mv != 0);
                cumj += (i <= off && on) ? 1 : 0;
                if (i == off) mj = on;
            }
            if (mj) ridx = cumj - 1;
        }
        rowsrc[tid] = ridx;
    }
    __syncthreads();

    // stage gathered rows (4 rows/iter, 64 lanes x float4 per row)
    const int rgrp   = tid >> 6;
    const int lane64 = tid & 63;
    for (int it = 0; it < 16; ++it) {
        int rl = it * 4 + rgrp;
        int ridx = rowsrc[rl];
        int cp   = lane64 >> 1;
        int half = lane64 & 1;
        f16x4 hv = {0, 0, 0, 0};
        if (ridx >= 0) {
            const float* s = tokens + ((size_t)b * TOKSTRIDE + NC + ridx) * EE + lane64 * 4;
            float4 v = *reinterpret_cast<const float4*>(s);
            hv[0] = (_Float16)v.x; hv[1] = (_Float16)v.y;
            hv[2] = (_Float16)v.z; hv[3] = (_Float16)v.w;
        }
        *reinterpret_cast<f16x4*>(xbase + rl * 512 + (((cp ^ (rl & 7)) << 4) | (half << 3))) = hv;
    }

    f16x8 bfrag[8];
    #pragma unroll
    for (int kt = 0; kt < 8; ++kt) {
        #pragma unroll
        for (int j = 0; j < 8; ++j) {
            int k = kt * 32 + kg * 8 + j;
            bfrag[kt][j] = (_Float16)Wf[k * 16 + colg];
        }
    }
    __syncthreads();

    const int arow = wave * 16 + colg;
    const char* xrow = xbase + arow * 512;
    const int swz = arow & 7;
    f32x4 acc = {0.f, 0.f, 0.f, 0.f};
    #pragma unroll
    for (int kt = 0; kt < 8; ++kt) {
        const int chunk = kt * 4 + kg;
        f16x8 a = *reinterpret_cast<const f16x8*>(xrow + ((chunk ^ swz) << 4));
        acc = __builtin_amdgcn_mfma_f32_16x16x32_f16(a, bfrag[kt], acc, 0, 0, 0);
    }

    const float bias = bf[colg];
    #pragma unroll
    for (int r = 0; r < 4; ++r) {
        int ol = wave * 16 + kg * 4 + r;
        int u  = u0 + ol;
        if (u < sa.nj) {
            float v = (rowsrc[ol] >= 0) ? (acc[r] + bias) : 0.f;
            patch_j[((size_t)b * sa.nj + u) * 16 + colg] = v;
        }
    }
}

// ---------------- K2: conv + blend + downsample; 2x2-quadrant conv taps ----------------
// 4 lanes/output (bilinear corners). The corners' 3x3 windows tile a 4x4
// union (i1 = i0+1, or i1 == i0 at the last index); each lane loads its 2x2
// quadrant and the remaining 5 taps arrive via shfl_xor(1/2/3) exchanges.
__global__ __launch_bounds__(256) void k_out(const float* __restrict__ coarse_img,
                                             const float* __restrict__ patch_j,
                                             const float* __restrict__ noise,
                                             const float* __restrict__ convw,
                                             float* __restrict__ out,
                                             SampArgs sa) {
    const int gt = blockIdx.x * 256 + threadIdx.x;    // 131072 threads
    const int o  = gt >> 2;                           // output index 0..32767
    const int corner = gt & 3;
    const int a = corner >> 1, c = corner & 1;

    const int b = o >> 10;
    const int p = (o >> 5) & 31;
    const int q = o & 31;

    float kk[9];
    #pragma unroll
    for (int i = 0; i < 9; ++i) kk[i] = convw[i];

    const int h0 = sa.i0[p], h1 = sa.i1[p];
    const int w0 = sa.i0[q], w1 = sa.i1[q];
    const int h = a ? h1 : h0;
    const int w = c ? w1 : w0;
    const int hgap = h1 - h0;                 // 1, or 0 at p==31 (wave-uniform)
    const int wgap = w1 - w0;                 // 1, or 0 at q==31 (per-lane)
    const float fh = sa.fr[p], fw = sa.fr[q];
    const float wt = (a ? fh : 1.f - fh) * (c ? fw : 1.f - fw);

    const float* cimg = coarse_img + (size_t)b*65536;
    const float* nimg = noise      + (size_t)b*65536;

    // own 2x2 quadrant of the 4x4 tap union
    const int rA = a ? h1 : h0 - 1;           // my row0 (row1 = rA+1)
    const int cA = c ? w  : w  - 1;           // my col0 (col1 = cA+1)
    auto ld = [&](int rr, int cc) -> float {
        return (rr >= 0 && rr < IMG && cc >= 0 && cc < IMG) ? cimg[rr*IMG + cc] : 0.f;
    };
    const float o00 = ld(rA,     cA);
    const float o01 = ld(rA,     cA + 1);
    const float o10 = ld(rA + 1, cA);
    const float o11 = ld(rA + 1, cA + 1);

    // exchanges: send the row/col my partner needs
    const int si = hgap ^ a;                  // row index to send (a-partner)
    const int sj = wgap ^ c;                  // col index to send (c-partner)
    float sC0 = sj ? o01 : o00, sC1 = sj ? o11 : o10;
    float nC0 = __shfl_xor(sC0, 1, 64), nC1 = __shfl_xor(sC1, 1, 64);
    float sA0 = si ? o10 : o00, sA1 = si ? o11 : o01;
    float nA0 = __shfl_xor(sA0, 2, 64), nA1 = __shfl_xor(sA1, 2, 64);
    float sD  = si ? (sj ? o11 : o10) : (sj ? o01 : o00);
    float nD  = __shfl_xor(sD, 3, 64);

    // assemble 3x3 (same fmaf order as before -> bitwise-identical conv)
    float conv = 0.f;
    #pragma unroll
    for (int i = 0; i < 3; ++i) {
        #pragma unroll
        for (int j = 0; j < 3; ++j) {
            const bool rN = a ? (i == 0) : (i == 2);
            const bool cN = c ? (j == 0) : (j == 2);
            const int ri = a ? i - 1 : i;     // 0/1 when !rN
            const int cj = c ? j - 1 : j;     // 0/1 when !cN
            const float own = (ri == 0) ? ((cj == 0) ? o00 : o01)
                                        : ((cj == 0) ? o10 : o11);
            const float tap = rN ? (cN ? nD : ((cj == 0) ? nA0 : nA1))
                                 : (cN ? ((ri == 0) ? nC0 : nC1) : own);
            conv = fmaf(tap, kk[i*3 + j], conv);
        }
    }

    const int jj = sa.inv[h >> 2] * sa.nhf + sa.inv[w >> 2];
    const int colx = (h & 3) * 4 + (w & 3);
    float fv = patch_j[((size_t)b * sa.nj + jj) * 16 + colx];

    float s = 1.f / (1.f + expf(-0.1f * nimg[h*IMG + w]));
    float val = wt * (conv * (1.f - s) + fv * s);

    val += __shfl_xor(val, 1, 64);
    val += __shfl_xor(val, 2, 64);
    if (corner == 0) out[o] = val;
}

extern "C" void kernel_launch(void* const* d_in, const int* in_sizes, int n_in,
                              void* d_out, int out_size, void* d_ws, size_t ws_size,
                              hipStream_t stream) {
    const float* tokens = (const float*)d_in[0];
    const int*   mask   = (const int*)  d_in[1];
    const float* Wc     = (const float*)d_in[2];
    const float* bc     = (const float*)d_in[3];
    const float* Wf     = (const float*)d_in[4];
    const float* bf     = (const float*)d_in[5];
    const float* convw  = (const float*)d_in[6];
    const float* noise  = (const float*)d_in[7];

    // interp + needed-hf structures (host, deterministic)
    SampArgs sa;
    bool need[64] = {false};
    for (int p = 0; p < 32; ++p) {
        double pos = (double)p * 255.0 / 31.0;
        int i0 = (int)floor(pos);
        int i1 = (i0 + 1 < 256) ? i0 + 1 : 255;
        sa.i0[p] = i0; sa.i1[p] = i1; sa.fr[p] = (float)(pos - (double)i0);
        need[i0 >> 2] = true; need[i1 >> 2] = true;
    }
    int nhf = 0;
    for (int hf = 0; hf < 64; ++hf) {
        sa.inv[hf] = 0;
        if (need[hf]) { sa.inv[hf] = nhf; sa.hfl[nhf++] = hf; }
    }
    for (int i = nhf; i < MAXHF; ++i) sa.hfl[i] = 0;
    sa.nhf = nhf;
    sa.nj  = nhf * nhf;
    sa.jblocks = (sa.nj + 63) / 64;

    float* ws = (float*)d_ws;
    float* coarse_img = ws;                               // 32*65536 floats
    float* patch_j    = ws + (size_t)BB*65536;            // 32*nj*16 floats

    k_mm <<<BB * sa.jblocks + 512, 256, 0, stream>>>(tokens, Wc, bc, Wf, bf,
                                                     mask, coarse_img, patch_j, sa);
    k_out<<<512, 256, 0, stream>>>(coarse_img, patch_j, noise, convw,
                                   (float*)d_out, sa);
}